// Round 11
// baseline (961.226 us; speedup 1.0000x reference)
//
#include <hip/hip_runtime.h>

// GCN 2-layer forward for MI355X — round 9/10/11: bucketed CSR fill.
//
// Round-8 (535 us): k_fill = 105 us, WRITE_SIZE 101 MB = 1.6M x 64B -> each
// random 8B scatter into the 12.8MB srt array wrote back a nearly-empty line
// (write targets span the whole array -> per-XCD L2 thrash).
// Fix: two-phase scatter. Pass A bins edges into 64-node buckets (1563
// sequential write cursors, ~100KB active dirty set, lines fill before
// eviction). Pass B walks bucketed edges linearly; each block's final srt
// writes land in a few 8KB node-windows (L2-resident). Writeback ~= the
// compulsory 12.8MB per pass instead of 101MB.
// Bucket buffer aliases the z region (dead until layer-1 pull).
// Scatter bounds are provable: each bucket/node cursor is incremented exactly
// its histogram count of times -> p always in [0, E). No OOB possible.

#define IN_DIM 128
#define H_DIM 48
#define O_DIM 32
#define BKT_SHIFT 6   // 64 nodes per bucket

__device__ __forceinline__ int clampi(int v, int hi) {
    return v < 0 ? 0 : (v >= hi ? hi - 1 : v);
}

// ======================= CSR build =======================

__global__ void k_zero_i32(int* __restrict__ p, int n) {
    int i = blockIdx.x * blockDim.x + threadIdx.x;
    if (i < n) p[i] = 0;
}

// fused node-degree + bucket histogram
__global__ void k_hist(const int* __restrict__ dst, int* __restrict__ cnt,
                       int* __restrict__ bhist, int E, int N) {
    int e = blockIdx.x * blockDim.x + threadIdx.x;
    if (e >= E) return;
    int d = clampi(dst[e], N);
    atomicAdd(&cnt[d], 1);
    atomicAdd(&bhist[d >> BKT_SHIFT], 1);
}

// block-level exclusive scan (1024/block): in -> out (local excl), totals -> bsum
__global__ __launch_bounds__(1024) void k_scan1(const int* __restrict__ in,
                                                int* __restrict__ out,
                                                int* __restrict__ bsum, int n) {
    __shared__ int sh[1024];
    const int tid = threadIdx.x;
    const int i = blockIdx.x * 1024 + tid;
    int v = (i < n) ? in[i] : 0;
    sh[tid] = v;
    __syncthreads();
    for (int off = 1; off < 1024; off <<= 1) {
        int t = (tid >= off) ? sh[tid - off] : 0;
        __syncthreads();
        sh[tid] += t;
        __syncthreads();
    }
    if (i < n) out[i] = sh[tid] - v;  // exclusive
    if (tid == 1023) bsum[blockIdx.x] = sh[1023];
}

// single-block exclusive scan of <=128 block totals (in place)
__global__ __launch_bounds__(128) void k_scan2(int* __restrict__ bsum, int nb) {
    __shared__ int sh[128];
    const int tid = threadIdx.x;
    int v = (tid < nb) ? bsum[tid] : 0;
    sh[tid] = v;
    __syncthreads();
    for (int off = 1; off < 128; off <<= 1) {
        int t = (tid >= off) ? sh[tid - off] : 0;
        __syncthreads();
        sh[tid] += t;
        __syncthreads();
    }
    if (tid < nb) bsum[tid] = sh[tid] - v;  // exclusive
}

// rp += block offset; cursor = rp; dis = rsqrt(1 + cnt); rp[n] = E
__global__ void k_scan3(int* __restrict__ rp, const int* __restrict__ bsum,
                        int* __restrict__ cur, const int* __restrict__ cnt,
                        float* __restrict__ dis, int n, int E) {
    int i = blockIdx.x * blockDim.x + threadIdx.x;
    if (i < n) {
        int r = rp[i] + bsum[i >> 10];
        rp[i] = r;
        cur[i] = r;
        dis[i] = rsqrtf(1.0f + (float)cnt[i]);
    }
    if (i == 0) rp[n] = E;
}

// boff += block offset; bcur = boff
__global__ void k_bfix(int* __restrict__ boff, const int* __restrict__ bsum2,
                       int* __restrict__ bcur, int nb) {
    int i = blockIdx.x * blockDim.x + threadIdx.x;
    if (i < nb) {
        int r = boff[i] + bsum2[i >> 10];
        boff[i] = r;
        bcur[i] = r;
    }
}

// pass A: scatter edges into 64-node buckets (payload {src, dst})
__global__ void k_passA(const int* __restrict__ src, const int* __restrict__ dst,
                        int* __restrict__ bcur, int2* __restrict__ buck,
                        int E, int N) {
    int e = blockIdx.x * blockDim.x + threadIdx.x;
    if (e >= E) return;
    int s = clampi(src[e], N);
    int d = clampi(dst[e], N);
    int p = atomicAdd(&bcur[d >> BKT_SHIFT], 1);
    buck[p] = make_int2(s, d);
}

// pass B: bucketed edges -> final dst-sorted order (payload {src, dis[src]})
__global__ void k_passB(const int2* __restrict__ buck, const float* __restrict__ dis,
                        int* __restrict__ cur, int2* __restrict__ srt, int E) {
    int i = blockIdx.x * blockDim.x + threadIdx.x;
    if (i >= E) return;
    int2 sd = buck[i];
    int p = atomicAdd(&cur[sd.y], 1);
    srt[p] = make_int2(sd.x, __float_as_int(dis[sd.x]));
}

// ======================= GEMM =======================

template <int K, int NO>
__global__ __launch_bounds__(256) void k_gemm(const float* __restrict__ X,
                                              const float* __restrict__ W,
                                              float* __restrict__ H, int n) {
    constexpr int BM = 32;
    constexpr int JPT = NO / 8;
    __shared__ float xs[BM * (K + 1)];
    __shared__ float ws[K * NO];

    const int t = threadIdx.x;
    const int node0 = blockIdx.x * BM;

    for (int i = t; i < K * NO; i += 256) ws[i] = W[i];
    for (int i = t; i < BM * K; i += 256) {
        int r = i / K, k = i % K;
        int node = node0 + r;
        xs[r * (K + 1) + k] = (node < n) ? X[(long long)node * K + k] : 0.0f;
    }
    __syncthreads();

    const int r = t >> 3;
    const int g = t & 7;
    float acc[JPT];
#pragma unroll
    for (int jj = 0; jj < JPT; jj++) acc[jj] = 0.0f;

    for (int k = 0; k < K; k++) {
        float xv = xs[r * (K + 1) + k];
#pragma unroll
        for (int jj = 0; jj < JPT; jj++) acc[jj] += xv * ws[k * NO + g * JPT + jj];
    }

    int node = node0 + r;
    if (node < n) {
#pragma unroll
        for (int jj = 0; jj < JPT; jj++)
            H[(long long)node * NO + g * JPT + jj] = acc[jj];
    }
}

// ======================= pull aggregation =======================
// One wave per dst node; acc = sum h[src]*dis[src]; final scale by dis[dst].

template <int F, bool RELU>
__global__ __launch_bounds__(256) void k_pull(const int2* __restrict__ srt,
                                              const int* __restrict__ rp,
                                              const float* __restrict__ dis,
                                              const float* __restrict__ hbuf,
                                              const float* __restrict__ bias,
                                              float* __restrict__ out, int N) {
    const int w = blockIdx.x * 4 + (threadIdx.x >> 6);
    if (w >= N) return;
    const int lane = threadIdx.x & 63;
    const int beg = rp[w];
    const int end = rp[w + 1];
    const float disd = dis[w];
    float acc = 0.0f;

    if (F == 48) {
        const int j = lane;
        if (j < F) {
            int e = beg;
            for (; e + 1 < end; e += 2) {
                int2 p0 = srt[e];
                int2 p1 = srt[e + 1];
                float v0 = hbuf[(size_t)p0.x * F + j];
                float v1 = hbuf[(size_t)p1.x * F + j];
                acc = fmaf(v0, __int_as_float(p0.y), acc);
                acc = fmaf(v1, __int_as_float(p1.y), acc);
            }
            if (e < end) {
                int2 p = srt[e];
                acc = fmaf(hbuf[(size_t)p.x * F + j], __int_as_float(p.y), acc);
            }
            float val = (acc + hbuf[(size_t)w * F + j] * disd) * disd + bias[j];
            if (RELU) val = fmaxf(val, 0.0f);
            out[(size_t)w * F + j] = val;
        }
    } else {  // F == 32
        const int j = lane & 31;
        const int half = lane >> 5;
        for (int e = beg + half; e < end; e += 2) {
            int2 p = srt[e];
            acc = fmaf(hbuf[(size_t)p.x * F + j], __int_as_float(p.y), acc);
        }
        acc += __shfl_xor(acc, 32);
        if (lane < 32) {
            float val = (acc + hbuf[(size_t)w * F + j] * disd) * disd + bias[j];
            if (RELU) val = fmaxf(val, 0.0f);
            out[(size_t)w * F + j] = val;
        }
    }
}

// ======================= fallback push path (round-6, proven) =======================

__global__ void k_init_deg(float* __restrict__ deg, int n) {
    int i = blockIdx.x * blockDim.x + threadIdx.x;
    if (i < n) deg[i] = 1.0f;
}

__global__ void k_deg_edges(const int* __restrict__ dst, float* __restrict__ deg,
                            int E, int N) {
    int e = blockIdx.x * blockDim.x + threadIdx.x;
    if (e < E) unsafeAtomicAdd(&deg[clampi(dst[e], N)], 1.0f);
}

__global__ void k_rsqrt_inplace(float* __restrict__ d, int n) {
    int i = blockIdx.x * blockDim.x + threadIdx.x;
    if (i < n) d[i] = rsqrtf(d[i]);
}

template <int F, bool BIAS>
__global__ void k_selfloop_init(const float* __restrict__ h, const float* __restrict__ dis,
                                const float* __restrict__ bias, float* __restrict__ out,
                                int total) {
    int i = blockIdx.x * blockDim.x + threadIdx.x;
    if (i >= total) return;
    int n = i / F;
    float d = dis[n];
    float v = h[i] * d * d;
    if (BIAS) v += bias[i % F];
    out[i] = v;
}

template <int F>
__global__ void k_agg(const int* __restrict__ src, const int* __restrict__ dst,
                      const float* __restrict__ dis, const float* __restrict__ h,
                      float* __restrict__ out, unsigned total, int N) {
    unsigned t = blockIdx.x * blockDim.x + threadIdx.x;
    if (t >= total) return;
    unsigned e = t / F;
    unsigned j = t - e * F;
    int s = clampi(src[e], N);
    int d = clampi(dst[e], N);
    float v = h[(long long)s * F + j] * (dis[s] * dis[d]);
    unsafeAtomicAdd(&out[(long long)d * F + j], v);
}

__global__ void k_bias_relu(float* __restrict__ z, const float* __restrict__ b, int total) {
    int i = blockIdx.x * blockDim.x + threadIdx.x;
    if (i >= total) return;
    z[i] = fmaxf(z[i] + b[i % H_DIM], 0.0f);
}

// ======================= launch =======================

static inline unsigned cdiv(unsigned a, unsigned b) { return (a + b - 1) / b; }

extern "C" void kernel_launch(void* const* d_in, const int* in_sizes, int n_in,
                              void* d_out, int out_size, void* d_ws, size_t ws_size,
                              hipStream_t stream) {
    const float* x = (const float*)d_in[0];
    const int* ei = (const int*)d_in[1];   // int32 (verified round 6)
    const float* W1 = (const float*)d_in[2];
    const float* b1 = (const float*)d_in[3];
    const float* W2 = (const float*)d_in[4];
    const float* b2 = (const float*)d_in[5];
    float* out = (float*)d_out;

    const int N = in_sizes[0] / IN_DIM;      // 100000
    const int E = in_sizes[1] / 2;           // 1600000
    const int* src = ei;
    const int* dst = ei + E;
    const int NB   = (int)cdiv(N, 1024);             // node-scan blocks (98)
    const int NBKT = (N + (1 << BKT_SHIFT) - 1) >> BKT_SHIFT;  // 1563
    const int NB2  = (int)cdiv(NBKT, 1024);          // bucket-scan blocks (2)

    const int B = 256;
    char* base = (char*)d_ws;

    // ---- pull-path carve ----
    size_t off = 0;
    auto carve = [&](size_t bytes) { size_t o = off; off = (off + bytes + 255) & ~(size_t)255; return o; };
    size_t o_dis   = carve((size_t)N * 4);
    size_t o_cnt   = carve((size_t)N * 4);
    size_t o_rp    = carve(((size_t)N + 1) * 4);
    size_t o_cur   = carve((size_t)N * 4);
    size_t o_bsum  = carve(256 * 4);
    size_t o_bsum2 = carve(256 * 4);
    size_t o_bhist = carve((size_t)NBKT * 4);
    size_t o_boff  = carve((size_t)NBKT * 4);
    size_t o_bcur  = carve((size_t)NBKT * 4);
    size_t o_srt   = carve((size_t)E * 8);
    size_t o_h     = carve((size_t)N * H_DIM * 4);
    size_t o_z     = carve((size_t)N * H_DIM * 4);
    size_t need_pull = off;
    bool buck_fits = (size_t)E * 8 <= (size_t)N * H_DIM * 4;  // buck aliases z

    if (ws_size >= need_pull && NB <= 128 && NB2 <= 128 && buck_fits) {
        float* dis  = (float*)(base + o_dis);
        int*   cnt  = (int*)(base + o_cnt);
        int*   rp   = (int*)(base + o_rp);
        int*   cur  = (int*)(base + o_cur);
        int*   bsm  = (int*)(base + o_bsum);
        int*   bsm2 = (int*)(base + o_bsum2);
        int*   bhist= (int*)(base + o_bhist);
        int*   boff = (int*)(base + o_boff);
        int*   bcur = (int*)(base + o_bcur);
        int2*  srt  = (int2*)(base + o_srt);
        float* h    = (float*)(base + o_h);
        float* z    = (float*)(base + o_z);
        int2*  buck = (int2*)(base + o_z);   // z dead until layer-1 pull
        float* h2   = h;                     // h1 dead once z built

        // histograms
        k_zero_i32<<<cdiv(N, B), B, 0, stream>>>(cnt, N);
        k_zero_i32<<<cdiv(NBKT, B), B, 0, stream>>>(bhist, NBKT);
        k_hist<<<cdiv(E, B), B, 0, stream>>>(dst, cnt, bhist, E, N);

        // node scan -> rp, cur, dis
        k_scan1<<<NB, 1024, 0, stream>>>(cnt, rp, bsm, N);
        k_scan2<<<1, 128, 0, stream>>>(bsm, NB);
        k_scan3<<<cdiv(N, B), B, 0, stream>>>(rp, bsm, cur, cnt, dis, N, E);

        // bucket scan -> boff, bcur
        k_scan1<<<NB2, 1024, 0, stream>>>(bhist, boff, bsm2, NBKT);
        k_scan2<<<1, 128, 0, stream>>>(bsm2, NB2);
        k_bfix<<<cdiv(NBKT, B), B, 0, stream>>>(boff, bsm2, bcur, NBKT);

        // two-phase fill
        k_passA<<<cdiv(E, B), B, 0, stream>>>(src, dst, bcur, buck, E, N);
        k_passB<<<cdiv(E, B), B, 0, stream>>>(buck, dis, cur, srt, E);

        // layer 1
        k_gemm<IN_DIM, H_DIM><<<cdiv(N, 32), B, 0, stream>>>(x, W1, h, N);
        k_pull<H_DIM, true><<<cdiv(N, 4), B, 0, stream>>>(srt, rp, dis, h, b1, z, N);

        // layer 2
        k_gemm<H_DIM, O_DIM><<<cdiv(N, 32), B, 0, stream>>>(z, W2, h2, N);
        k_pull<O_DIM, false><<<cdiv(N, 4), B, 0, stream>>>(srt, rp, dis, h2, b2, out, N);
        return;
    }

    // ---- fallback: proven round-6 push path ----
    auto align_up = [](size_t v) { return (v + 63) & ~(size_t)63; };
    size_t f_dis = 0;
    size_t f_h   = f_dis + align_up((size_t)N);
    size_t f_z   = f_h + align_up((size_t)N * H_DIM);
    size_t need_push = (f_z + align_up((size_t)N * H_DIM)) * sizeof(float);
    if (ws_size < need_push) return;

    float* dis = (float*)d_ws + f_dis;
    float* h   = (float*)d_ws + f_h;
    float* z   = (float*)d_ws + f_z;
    float* h2  = h;

    k_init_deg<<<cdiv(N, B), B, 0, stream>>>(dis, N);
    k_deg_edges<<<cdiv(E, B), B, 0, stream>>>(dst, dis, E, N);
    k_rsqrt_inplace<<<cdiv(N, B), B, 0, stream>>>(dis, N);

    k_gemm<IN_DIM, H_DIM><<<cdiv(N, 32), B, 0, stream>>>(x, W1, h, N);
    k_selfloop_init<H_DIM, false><<<cdiv(N * H_DIM, B), B, 0, stream>>>(h, dis, b1, z, N * H_DIM);
    k_agg<H_DIM><<<cdiv((unsigned)E * H_DIM, B), B, 0, stream>>>(src, dst, dis, h, z, (unsigned)E * H_DIM, N);
    k_bias_relu<<<cdiv(N * H_DIM, B), B, 0, stream>>>(z, b1, N * H_DIM);

    k_gemm<H_DIM, O_DIM><<<cdiv(N, 32), B, 0, stream>>>(z, W2, h2, N);
    k_selfloop_init<O_DIM, true><<<cdiv(N * O_DIM, B), B, 0, stream>>>(h2, dis, b2, out, N * O_DIM);
    k_agg<O_DIM><<<cdiv((unsigned)E * O_DIM, B), B, 0, stream>>>(src, dst, dis, h2, out, (unsigned)E * O_DIM, N);
}

// Round 13
// 548.481 us; speedup vs baseline: 1.7525x; 1.7525x over previous
//
#include <hip/hip_runtime.h>

// GCN 2-layer forward for MI355X — round 12/13: round-8 pipeline + 4B fill payload.
//
// History:
//  R6  push-atomics baseline 703 us (k_agg = 300 G atomics/s wall).
//  R8  CSR pull 535 us; k_fill 105 us (WRITE 101 MB: random 8B scatter dirties
//      64B lines across the whole 12.8MB srt -> ~8x write amplification).
//  R11 bucketed fill REGRESSED to 961 us: atomics onto 1563-counter arrays
//      (bhist/bcur) serialize per cache line (~98 lines, ~16K-deep chains).
//      LESSON: per-edge atomics OK at >=100K counters, fatal at ~1K.
// This round: single-phase fill (proven), payload slimmed int2->int (src only)
// -> half the dirtied lines; pull loads dis[src] as a wave-broadcast L2 hit.

#define IN_DIM 128
#define H_DIM 48
#define O_DIM 32

__device__ __forceinline__ int clampi(int v, int hi) {
    return v < 0 ? 0 : (v >= hi ? hi - 1 : v);
}

// ======================= CSR build =======================

__global__ void k_zero_i32(int* __restrict__ p, int n) {
    int i = blockIdx.x * blockDim.x + threadIdx.x;
    if (i < n) p[i] = 0;
}

// per-node in-degree histogram (100K counters: proven-cheap contention)
__global__ void k_count(const int* __restrict__ dst, int* __restrict__ cnt,
                        int E, int N) {
    int e = blockIdx.x * blockDim.x + threadIdx.x;
    if (e < E) atomicAdd(&cnt[clampi(dst[e], N)], 1);
}

// block-level exclusive scan (1024/block): in -> out (local excl), totals -> bsum
__global__ __launch_bounds__(1024) void k_scan1(const int* __restrict__ in,
                                                int* __restrict__ out,
                                                int* __restrict__ bsum, int n) {
    __shared__ int sh[1024];
    const int tid = threadIdx.x;
    const int i = blockIdx.x * 1024 + tid;
    int v = (i < n) ? in[i] : 0;
    sh[tid] = v;
    __syncthreads();
    for (int off = 1; off < 1024; off <<= 1) {
        int t = (tid >= off) ? sh[tid - off] : 0;
        __syncthreads();
        sh[tid] += t;
        __syncthreads();
    }
    if (i < n) out[i] = sh[tid] - v;  // exclusive
    if (tid == 1023) bsum[blockIdx.x] = sh[1023];
}

// single-block exclusive scan of <=128 block totals (in place)
__global__ __launch_bounds__(128) void k_scan2(int* __restrict__ bsum, int nb) {
    __shared__ int sh[128];
    const int tid = threadIdx.x;
    int v = (tid < nb) ? bsum[tid] : 0;
    sh[tid] = v;
    __syncthreads();
    for (int off = 1; off < 128; off <<= 1) {
        int t = (tid >= off) ? sh[tid - off] : 0;
        __syncthreads();
        sh[tid] += t;
        __syncthreads();
    }
    if (tid < nb) bsum[tid] = sh[tid] - v;  // exclusive
}

// rp += block offset; cursor = rp; dis = rsqrt(1 + cnt); rp[n] = E
__global__ void k_scan3(int* __restrict__ rp, const int* __restrict__ bsum,
                        int* __restrict__ cur, const int* __restrict__ cnt,
                        float* __restrict__ dis, int n, int E) {
    int i = blockIdx.x * blockDim.x + threadIdx.x;
    if (i < n) {
        int r = rp[i] + bsum[i >> 10];
        rp[i] = r;
        cur[i] = r;
        dis[i] = rsqrtf(1.0f + (float)cnt[i]);
    }
    if (i == 0) rp[n] = E;
}

// scatter edges into dst-sorted order; payload = src only (4B)
__global__ void k_fill(const int* __restrict__ src, const int* __restrict__ dst,
                       int* __restrict__ cur, int* __restrict__ srt, int E, int N) {
    int e = blockIdx.x * blockDim.x + threadIdx.x;
    if (e >= E) return;
    int s = clampi(src[e], N);
    int d = clampi(dst[e], N);
    int p = atomicAdd(&cur[d], 1);
    srt[p] = s;
}

// ======================= GEMM =======================

template <int K, int NO>
__global__ __launch_bounds__(256) void k_gemm(const float* __restrict__ X,
                                              const float* __restrict__ W,
                                              float* __restrict__ H, int n) {
    constexpr int BM = 32;
    constexpr int JPT = NO / 8;
    __shared__ float xs[BM * (K + 1)];
    __shared__ float ws[K * NO];

    const int t = threadIdx.x;
    const int node0 = blockIdx.x * BM;

    for (int i = t; i < K * NO; i += 256) ws[i] = W[i];
    for (int i = t; i < BM * K; i += 256) {
        int r = i / K, k = i % K;
        int node = node0 + r;
        xs[r * (K + 1) + k] = (node < n) ? X[(long long)node * K + k] : 0.0f;
    }
    __syncthreads();

    const int r = t >> 3;
    const int g = t & 7;
    float acc[JPT];
#pragma unroll
    for (int jj = 0; jj < JPT; jj++) acc[jj] = 0.0f;

    for (int k = 0; k < K; k++) {
        float xv = xs[r * (K + 1) + k];
#pragma unroll
        for (int jj = 0; jj < JPT; jj++) acc[jj] += xv * ws[k * NO + g * JPT + jj];
    }

    int node = node0 + r;
    if (node < n) {
#pragma unroll
        for (int jj = 0; jj < JPT; jj++)
            H[(long long)node * NO + g * JPT + jj] = acc[jj];
    }
}

// ======================= pull aggregation =======================
// One wave per dst node; acc = sum h[src]*dis[src]; final scale by dis[dst].
// dis[src] load is same-address across the feature lanes -> broadcast hit.

template <int F, bool RELU>
__global__ __launch_bounds__(256) void k_pull(const int* __restrict__ srt,
                                              const int* __restrict__ rp,
                                              const float* __restrict__ dis,
                                              const float* __restrict__ hbuf,
                                              const float* __restrict__ bias,
                                              float* __restrict__ out, int N) {
    const int w = blockIdx.x * 4 + (threadIdx.x >> 6);
    if (w >= N) return;
    const int lane = threadIdx.x & 63;
    const int beg = rp[w];
    const int end = rp[w + 1];
    const float disd = dis[w];
    float acc = 0.0f;

    if (F == 48) {
        const int j = lane;
        if (j < F) {
            int e = beg;
            for (; e + 1 < end; e += 2) {
                int s0 = srt[e];
                int s1 = srt[e + 1];
                float w0 = dis[s0];
                float w1 = dis[s1];
                acc = fmaf(hbuf[(size_t)s0 * F + j], w0, acc);
                acc = fmaf(hbuf[(size_t)s1 * F + j], w1, acc);
            }
            if (e < end) {
                int s0 = srt[e];
                acc = fmaf(hbuf[(size_t)s0 * F + j], dis[s0], acc);
            }
            float val = (acc + hbuf[(size_t)w * F + j] * disd) * disd + bias[j];
            if (RELU) val = fmaxf(val, 0.0f);
            out[(size_t)w * F + j] = val;
        }
    } else {  // F == 32
        const int j = lane & 31;
        const int half = lane >> 5;
        for (int e = beg + half; e < end; e += 2) {
            int s0 = srt[e];
            acc = fmaf(hbuf[(size_t)s0 * F + j], dis[s0], acc);
        }
        acc += __shfl_xor(acc, 32);
        if (lane < 32) {
            float val = (acc + hbuf[(size_t)w * F + j] * disd) * disd + bias[j];
            if (RELU) val = fmaxf(val, 0.0f);
            out[(size_t)w * F + j] = val;
        }
    }
}

// ======================= fallback push path (round-6, proven) =======================

__global__ void k_init_deg(float* __restrict__ deg, int n) {
    int i = blockIdx.x * blockDim.x + threadIdx.x;
    if (i < n) deg[i] = 1.0f;
}

__global__ void k_deg_edges(const int* __restrict__ dst, float* __restrict__ deg,
                            int E, int N) {
    int e = blockIdx.x * blockDim.x + threadIdx.x;
    if (e < E) unsafeAtomicAdd(&deg[clampi(dst[e], N)], 1.0f);
}

__global__ void k_rsqrt_inplace(float* __restrict__ d, int n) {
    int i = blockIdx.x * blockDim.x + threadIdx.x;
    if (i < n) d[i] = rsqrtf(d[i]);
}

template <int F, bool BIAS>
__global__ void k_selfloop_init(const float* __restrict__ h, const float* __restrict__ dis,
                                const float* __restrict__ bias, float* __restrict__ out,
                                int total) {
    int i = blockIdx.x * blockDim.x + threadIdx.x;
    if (i >= total) return;
    int n = i / F;
    float d = dis[n];
    float v = h[i] * d * d;
    if (BIAS) v += bias[i % F];
    out[i] = v;
}

template <int F>
__global__ void k_agg(const int* __restrict__ src, const int* __restrict__ dst,
                      const float* __restrict__ dis, const float* __restrict__ h,
                      float* __restrict__ out, unsigned total, int N) {
    unsigned t = blockIdx.x * blockDim.x + threadIdx.x;
    if (t >= total) return;
    unsigned e = t / F;
    unsigned j = t - e * F;
    int s = clampi(src[e], N);
    int d = clampi(dst[e], N);
    float v = h[(long long)s * F + j] * (dis[s] * dis[d]);
    unsafeAtomicAdd(&out[(long long)d * F + j], v);
}

__global__ void k_bias_relu(float* __restrict__ z, const float* __restrict__ b, int total) {
    int i = blockIdx.x * blockDim.x + threadIdx.x;
    if (i >= total) return;
    z[i] = fmaxf(z[i] + b[i % H_DIM], 0.0f);
}

// ======================= launch =======================

static inline unsigned cdiv(unsigned a, unsigned b) { return (a + b - 1) / b; }

extern "C" void kernel_launch(void* const* d_in, const int* in_sizes, int n_in,
                              void* d_out, int out_size, void* d_ws, size_t ws_size,
                              hipStream_t stream) {
    const float* x = (const float*)d_in[0];
    const int* ei = (const int*)d_in[1];   // int32 (verified round 6)
    const float* W1 = (const float*)d_in[2];
    const float* b1 = (const float*)d_in[3];
    const float* W2 = (const float*)d_in[4];
    const float* b2 = (const float*)d_in[5];
    float* out = (float*)d_out;

    const int N = in_sizes[0] / IN_DIM;      // 100000
    const int E = in_sizes[1] / 2;           // 1600000
    const int* src = ei;
    const int* dst = ei + E;
    const int NB = (int)cdiv(N, 1024);       // node-scan blocks (98)

    const int B = 256;
    char* base = (char*)d_ws;

    // ---- pull-path carve ----
    size_t off = 0;
    auto carve = [&](size_t bytes) { size_t o = off; off = (off + bytes + 255) & ~(size_t)255; return o; };
    size_t o_dis  = carve((size_t)N * 4);
    size_t o_cnt  = carve((size_t)N * 4);
    size_t o_rp   = carve(((size_t)N + 1) * 4);
    size_t o_cur  = carve((size_t)N * 4);
    size_t o_bsum = carve(256 * 4);
    size_t o_srt  = carve((size_t)E * 4);
    size_t o_h    = carve((size_t)N * H_DIM * 4);
    size_t o_z    = carve((size_t)N * H_DIM * 4);
    size_t need_pull = off;

    if (ws_size >= need_pull && NB <= 128) {
        float* dis = (float*)(base + o_dis);
        int*   cnt = (int*)(base + o_cnt);
        int*   rp  = (int*)(base + o_rp);
        int*   cur = (int*)(base + o_cur);
        int*   bsm = (int*)(base + o_bsum);
        int*   srt = (int*)(base + o_srt);
        float* h   = (float*)(base + o_h);
        float* z   = (float*)(base + o_z);
        float* h2  = h;  // h1 dead once z built

        // CSR build
        k_zero_i32<<<cdiv(N, B), B, 0, stream>>>(cnt, N);
        k_count<<<cdiv(E, B), B, 0, stream>>>(dst, cnt, E, N);
        k_scan1<<<NB, 1024, 0, stream>>>(cnt, rp, bsm, N);
        k_scan2<<<1, 128, 0, stream>>>(bsm, NB);
        k_scan3<<<cdiv(N, B), B, 0, stream>>>(rp, bsm, cur, cnt, dis, N, E);
        k_fill<<<cdiv(E, B), B, 0, stream>>>(src, dst, cur, srt, E, N);

        // layer 1
        k_gemm<IN_DIM, H_DIM><<<cdiv(N, 32), B, 0, stream>>>(x, W1, h, N);
        k_pull<H_DIM, true><<<cdiv(N, 4), B, 0, stream>>>(srt, rp, dis, h, b1, z, N);

        // layer 2
        k_gemm<H_DIM, O_DIM><<<cdiv(N, 32), B, 0, stream>>>(z, W2, h2, N);
        k_pull<O_DIM, false><<<cdiv(N, 4), B, 0, stream>>>(srt, rp, dis, h2, b2, out, N);
        return;
    }

    // ---- fallback: proven round-6 push path ----
    auto align_up = [](size_t v) { return (v + 63) & ~(size_t)63; };
    size_t f_dis = 0;
    size_t f_h   = f_dis + align_up((size_t)N);
    size_t f_z   = f_h + align_up((size_t)N * H_DIM);
    size_t need_push = (f_z + align_up((size_t)N * H_DIM)) * sizeof(float);
    if (ws_size < need_push) return;

    float* dis = (float*)d_ws + f_dis;
    float* h   = (float*)d_ws + f_h;
    float* z   = (float*)d_ws + f_z;
    float* h2  = h;

    k_init_deg<<<cdiv(N, B), B, 0, stream>>>(dis, N);
    k_deg_edges<<<cdiv(E, B), B, 0, stream>>>(dst, dis, E, N);
    k_rsqrt_inplace<<<cdiv(N, B), B, 0, stream>>>(dis, N);

    k_gemm<IN_DIM, H_DIM><<<cdiv(N, 32), B, 0, stream>>>(x, W1, h, N);
    k_selfloop_init<H_DIM, false><<<cdiv(N * H_DIM, B), B, 0, stream>>>(h, dis, b1, z, N * H_DIM);
    k_agg<H_DIM><<<cdiv((unsigned)E * H_DIM, B), B, 0, stream>>>(src, dst, dis, h, z, (unsigned)E * H_DIM, N);
    k_bias_relu<<<cdiv(N * H_DIM, B), B, 0, stream>>>(z, b1, N * H_DIM);

    k_gemm<H_DIM, O_DIM><<<cdiv(N, 32), B, 0, stream>>>(z, W2, h2, N);
    k_selfloop_init<O_DIM, true><<<cdiv(N * O_DIM, B), B, 0, stream>>>(h2, dis, b2, out, N * O_DIM);
    k_agg<O_DIM><<<cdiv((unsigned)E * O_DIM, B), B, 0, stream>>>(src, dst, dis, h2, out, (unsigned)E * O_DIM, N);
}